// Round 8
// baseline (165.354 us; speedup 1.0000x reference)
//
#include <hip/hip_runtime.h>

#define NTOK 1600
#define BT_TOTAL 8
#define INNER 128
#define HD 32
#define NH 4
#define QDIM 256

typedef short short8 __attribute__((ext_vector_type(8)));
typedef short short4v __attribute__((ext_vector_type(4)));
typedef float f32x4 __attribute__((ext_vector_type(4)));
typedef float f32x16 __attribute__((ext_vector_type(16)));

__device__ inline short f2b(float x) {  // fp32 -> bf16, RNE (final stores)
  union { float f; unsigned u; } v; v.f = x;
  unsigned r = (v.u + 0x7FFF + ((v.u >> 16) & 1)) >> 16;
  return (short)r;
}
// bf16(a) low 16, bf16(b) high 16; round-half-up via v_perm (3 VALU)
__device__ inline unsigned bpack2(float a, float b) {
  union { float f; unsigned u; } ua, ub;
  ua.f = a; ub.f = b;
  return __builtin_amdgcn_perm(ub.u + 0x8000u, ua.u + 0x8000u, 0x07060302u);
}
__device__ inline short8 mk8(unsigned a, unsigned b, unsigned c, unsigned d) {
  union { unsigned u[4]; short8 v; } t;
  t.u[0] = a; t.u[1] = b; t.u[2] = c; t.u[3] = d;
  return t.v;
}
__device__ inline f32x16 zero16() {
  return (f32x16){0.f, 0.f, 0.f, 0.f, 0.f, 0.f, 0.f, 0.f,
                  0.f, 0.f, 0.f, 0.f, 0.f, 0.f, 0.f, 0.f};
}
// Build a 32x32x16 MFMA operand fragment from an fp32 matrix stored
// [k][col] with row stride rs: lane (q32, lh) holds elems k=kbase+lh*8+0..7
// at column col. 8 coalesced dword loads + 4 packs. Layout verified by R7
// attn (identical indexing as its K/Q token-major fragment loads).
__device__ inline short8 fragf32(const float* __restrict__ base, int rs,
                                 int col, int kbase, int lh) {
  unsigned d[4];
#pragma unroll
  for (int e = 0; e < 4; ++e) {
    float f0 = base[(size_t)(kbase + lh * 8 + 2 * e) * rs + col];
    float f1 = base[(size_t)(kbase + lh * 8 + 2 * e + 1) * rs + col];
    d[e] = bpack2(f0, f1);
  }
  return mk8(d[0], d[1], d[2], d[3]);
}

// ---- QKV projection: one wave per 32x32 output tile, no LDS, no barriers --
// grid 1200 x 256: wg = blockIdx.x*4+wave in [0,4800).
//   which = wg/1600 (0=Q,1=K,2=V); bt = rem/200; ot = out-tile; tt = tok-tile
// Q,K out token-major [bt][h][tok][32] (Q scaled); V out d-major [bt][i][tok]
// D[m][n] = sum_k A[m][k] B[n][k]; C row = (r&3)+8*(r>>2)+4*lh, col = q32.
__global__ __launch_bounds__(256) void proj_direct(
    const float* __restrict__ query, const float* __restrict__ Wq,
    const float* __restrict__ key, const float* __restrict__ Wk,
    const float* __restrict__ value, const float* __restrict__ Wv,
    short* __restrict__ Qbf, short* __restrict__ Kbf,
    short* __restrict__ Vbf) {
  const int wave = threadIdx.x >> 6, lane = threadIdx.x & 63;
  const int lh = lane >> 5, q32 = lane & 31;
  const int wg = blockIdx.x * 4 + wave;
  const int which = wg / 1600;
  int rem = wg - which * 1600;
  const int bt = rem / 200;
  const int t8 = rem - bt * 200;
  const int ot = t8 / 50;            // out-tile (0..3)
  const int tt = t8 - ot * 50;       // tok-tile (0..49)

  const float* aBase; const float* bBase;
  int aStride, bStride, aCol, bCol, nk;
  if (which == 0) {
    aBase = query + (size_t)bt * QDIM * NTOK; aStride = NTOK;
    aCol = tt * 32 + q32;
    bBase = Wq; bStride = INNER; bCol = ot * 32 + q32; nk = 16;
  } else if (which == 1) {
    aBase = key + (size_t)bt * INNER * NTOK; aStride = NTOK;
    aCol = tt * 32 + q32;
    bBase = Wk; bStride = INNER; bCol = ot * 32 + q32; nk = 8;
  } else {
    aBase = Wv; aStride = INNER; aCol = ot * 32 + q32;
    bBase = value + (size_t)bt * INNER * NTOK; bStride = NTOK;
    bCol = tt * 32 + q32; nk = 8;
  }

  f32x16 acc = zero16();
#pragma unroll 4
  for (int ks = 0; ks < nk; ++ks) {
    short8 a = fragf32(aBase, aStride, aCol, ks * 16, lh);
    short8 b = fragf32(bBase, bStride, bCol, ks * 16, lh);
    acc = __builtin_amdgcn_mfma_f32_32x32x16_bf16(a, b, acc, 0, 0, 0);
  }

  if (which != 2) {
    // token-major: m = tok (rows), n = outd (cols, one head = 32)
    short* Yb = ((which == 0) ? Qbf : Kbf) +
                ((size_t)(bt * NH + ot) * NTOK) * HD;
    const float scl = (which == 0) ? 0.17677669529663687f : 1.0f;
    const int tokbase = tt * 32;
#pragma unroll
    for (int r = 0; r < 16; ++r) {
      int row = (r & 3) + 8 * (r >> 2) + 4 * lh;
      Yb[(size_t)(tokbase + row) * HD + q32] = f2b(acc[r] * scl);
    }
  } else {
    // d-major: m = i (rows), n = tok (cols)
#pragma unroll
    for (int r = 0; r < 16; ++r) {
      int irow = ot * 32 + (r & 3) + 8 * (r >> 2) + 4 * lh;
      Vbf[((size_t)bt * INNER + irow) * NTOK + tt * 32 + q32] = f2b(acc[r]);
    }
  }
}

// ---- MFMA attention (unchanged from R7) -----------------------------------
__global__ __launch_bounds__(256, 5) void attn_mfma(
    const short* __restrict__ Qb, const short* __restrict__ Kb,
    const short* __restrict__ Vb, short* __restrict__ Obf) {
  const int id = blockIdx.x;
  const int qt = id >> 5;
  const int pair = id & 31;
  const int bt = pair >> 2, h = pair & 3;
  const int wave = threadIdx.x >> 6, lane = threadIdx.x & 63;
  const int lh = lane >> 5, q32 = lane & 31;
  const int q0 = qt * 32;
  const size_t btok = ((size_t)bt * NH + h) * NTOK;
  const size_t bd = ((size_t)bt * NH + h) * HD;
  const bool hi = (lane >= 32);

  __shared__ float Cb[2][17][64];  // 8.5 KB combine buffers

  const short* Qp = &Qb[(btok + q0 + q32) * HD + lh * 8];
  const short8 bq0 = *(const short8*)(Qp);
  const short8 bq1 = *(const short8*)(Qp + 16);

  const int kstart = wave * 416 - (wave == 3 ? 32 : 0);
  const int nch = 13 - (wave >> 1);
  const short* Kp = &Kb[(btok + kstart + q32) * HD + lh * 8];
  const short* Vp = &Vb[(bd + q32) * NTOK + kstart + lh * 8];

  f32x16 o = zero16();
  float lsum = 0.f;

  short8 ak0 = *(const short8*)(Kp);
  short8 ak1 = *(const short8*)(Kp + 16);

  for (int i = 0; i < nch; ++i) {
    const int kc = i * 32;
    const int kn = (i + 1 < nch) ? kc + 32 : 0;
    short8 nk0 = *(const short8*)(Kp + (size_t)kn * HD);
    short8 nk1 = *(const short8*)(Kp + (size_t)kn * HD + 16);
    short8 av0 = *(const short8*)(Vp + kc);
    short8 av1 = *(const short8*)(Vp + kc + 16);

    f32x16 s = __builtin_amdgcn_mfma_f32_32x32x16_bf16(ak0, bq0, zero16(),
                                                       0, 0, 0);
    s = __builtin_amdgcn_mfma_f32_32x32x16_bf16(ak1, bq1, s, 0, 0, 0);

    unsigned Pd[8];
#pragma unroll
    for (int g = 0; g < 4; ++g) {
      float e0 = __expf(s[4 * g + 0]);
      float e1 = __expf(s[4 * g + 1]);
      float e2 = __expf(s[4 * g + 2]);
      float e3 = __expf(s[4 * g + 3]);
      lsum += (e0 + e1) + (e2 + e3);
      Pd[2 * g + 0] = bpack2(e0, e1);
      Pd[2 * g + 1] = bpack2(e2, e3);
    }
    unsigned Xd[8];
#pragma unroll
    for (int j = 0; j < 8; ++j)
      Xd[j] = (unsigned)__shfl_xor((int)Pd[j], 32);
    short8 pb0 = mk8(hi ? Xd[2] : Pd[0], hi ? Xd[3] : Pd[1],
                     hi ? Pd[2] : Xd[0], hi ? Pd[3] : Xd[1]);
    short8 pb1 = mk8(hi ? Xd[6] : Pd[4], hi ? Xd[7] : Pd[5],
                     hi ? Pd[6] : Xd[4], hi ? Pd[7] : Xd[5]);

    o = __builtin_amdgcn_mfma_f32_32x32x16_bf16(av0, pb0, o, 0, 0, 0);
    o = __builtin_amdgcn_mfma_f32_32x32x16_bf16(av1, pb1, o, 0, 0, 0);
    ak0 = nk0; ak1 = nk1;
  }

  lsum += __shfl_xor(lsum, 32);

  auto dump = [&](int sidx) {
#pragma unroll
    for (int r = 0; r < 16; ++r) Cb[sidx][r][lane] = o[r];
    Cb[sidx][16][lane] = lsum;
  };
  auto accum = [&](int sidx) {
#pragma unroll
    for (int r = 0; r < 16; ++r) o[r] += Cb[sidx][r][lane];
    lsum += Cb[sidx][16][lane];
  };
  if (wave == 1) dump(0);
  if (wave == 3) dump(1);
  __syncthreads();
  if (wave == 0) accum(0);
  if (wave == 2) accum(1);
  __syncthreads();
  if (wave == 2) dump(0);
  __syncthreads();
  if (wave == 0) {
    accum(0);
    const float inv = 1.f / lsum;
    short* Op = &Obf[((size_t)bt * NTOK + q0 + q32) * INNER + h * HD + lh * 4];
#pragma unroll
    for (int g = 0; g < 4; ++g) {
      unsigned d0 = bpack2(o[4 * g + 0] * inv, o[4 * g + 1] * inv);
      unsigned d1 = bpack2(o[4 * g + 2] * inv, o[4 * g + 3] * inv);
      *(uint2*)&Op[8 * g] = make_uint2(d0, d1);
    }
  }
}

// ---- output projection: one wave per 32dout x 32tok tile, no LDS ----------
// grid 800 x 256: wg in [0,3200): bt = wg/400; dt = out-tile; tt = tok-tile.
// A[m=dout][k=i] = Wo[i][dout] (fp32 frag); B[n=tok][k=i] = O[tok][i]
// (bf16 token-major -> single 16B load per k-step).
__global__ __launch_bounds__(256) void oproj_direct(
    const short* __restrict__ Obf, const float* __restrict__ Wo,
    const float* __restrict__ bo, float* __restrict__ out) {
  const int wave = threadIdx.x >> 6, lane = threadIdx.x & 63;
  const int lh = lane >> 5, q32 = lane & 31;
  const int wg = blockIdx.x * 4 + wave;
  const int bt = wg / 400;
  int rem = wg - bt * 400;
  const int dt = rem / 50;
  const int tt = rem - dt * 50;
  const int d0 = dt * 32;
  const int tok = tt * 32 + q32;

  f32x16 acc = zero16();
#pragma unroll
  for (int ks = 0; ks < 8; ++ks) {
    short8 a = fragf32(Wo, QDIM, d0 + q32, ks * 16, lh);
    short8 b = *(const short8*)&Obf[((size_t)bt * NTOK + tok) * INNER +
                                    ks * 16 + lh * 8];
    acc = __builtin_amdgcn_mfma_f32_32x32x16_bf16(a, b, acc, 0, 0, 0);
  }
#pragma unroll
  for (int r = 0; r < 16; ++r) {
    int row = d0 + (r & 3) + 8 * (r >> 2) + 4 * lh;
    out[((size_t)bt * QDIM + row) * NTOK + tok] = acc[r] + bo[row];
  }
}

extern "C" void kernel_launch(void* const* d_in, const int* in_sizes, int n_in,
                              void* d_out, int out_size, void* d_ws,
                              size_t ws_size, hipStream_t stream) {
  const float* query = (const float*)d_in[0];
  const float* key = (const float*)d_in[1];
  const float* value = (const float*)d_in[2];
  const float* Wq = (const float*)d_in[3];
  const float* Wk = (const float*)d_in[4];
  const float* Wv = (const float*)d_in[5];
  const float* Wo = (const float*)d_in[6];
  const float* bo = (const float*)d_in[7];
  float* out = (float*)d_out;

  const size_t arr = (size_t)BT_TOTAL * INNER * NTOK;
  short* Qbf = (short*)d_ws;
  short* Kbf = Qbf + arr;
  short* Vbf = Kbf + arr;
  short* Obf = Vbf + arr;

  proj_direct<<<dim3(1200), 256, 0, stream>>>(query, Wq, key, Wk, value, Wv,
                                              Qbf, Kbf, Vbf);
  attn_mfma<<<dim3(1600), 256, 0, stream>>>(Qbf, Kbf, Vbf, Obf);
  oproj_direct<<<dim3(800), 256, 0, stream>>>(Obf, Wo, bo, out);
}

// Round 9
// 145.150 us; speedup vs baseline: 1.1392x; 1.1392x over previous
//
#include <hip/hip_runtime.h>

#define NTOK 1600
#define BT_TOTAL 8
#define INNER 128
#define HD 32
#define NH 4
#define QDIM 256

typedef short short8 __attribute__((ext_vector_type(8)));
typedef short short4v __attribute__((ext_vector_type(4)));
typedef float f32x4 __attribute__((ext_vector_type(4)));
typedef float f32x16 __attribute__((ext_vector_type(16)));

__device__ inline short f2b(float x) {  // fp32 -> bf16, RNE (final stores)
  union { float f; unsigned u; } v; v.f = x;
  unsigned r = (v.u + 0x7FFF + ((v.u >> 16) & 1)) >> 16;
  return (short)r;
}
// bf16(a) low 16, bf16(b) high 16; round-half-up via v_perm (3 VALU)
__device__ inline unsigned bpack2(float a, float b) {
  union { float f; unsigned u; } ua, ub;
  ua.f = a; ub.f = b;
  return __builtin_amdgcn_perm(ub.u + 0x8000u, ua.u + 0x8000u, 0x07060302u);
}
__device__ inline short8 mk8(unsigned a, unsigned b, unsigned c, unsigned d) {
  union { unsigned u[4]; short8 v; } t;
  t.u[0] = a; t.u[1] = b; t.u[2] = c; t.u[3] = d;
  return t.v;
}
__device__ inline f32x16 zero16() {
  return (f32x16){0.f, 0.f, 0.f, 0.f, 0.f, 0.f, 0.f, 0.f,
                  0.f, 0.f, 0.f, 0.f, 0.f, 0.f, 0.f, 0.f};
}
__device__ inline short8 packfrag(const float* x) {
  return mk8(bpack2(x[0], x[1]), bpack2(x[2], x[3]), bpack2(x[4], x[5]),
             bpack2(x[6], x[7]));
}

// ---- weight pre-convert: W[k][n] fp32 -> WT[n][k] bf16 --------------------
// grid 192 x 256. Coalesced reads along n; writes land in L2 (196 KB total).
__global__ __launch_bounds__(256) void wconv(
    const float* __restrict__ Wq, const float* __restrict__ Wk,
    const float* __restrict__ Wv, const float* __restrict__ Wo,
    short* __restrict__ WqT, short* __restrict__ WkT,
    short* __restrict__ WvT, short* __restrict__ WoT) {
  int i = blockIdx.x * 256 + threadIdx.x;
  const float* W; short* WT; int NN, rem;
  if (i < 16384) { W = Wq; WT = WqT; NN = 128; rem = i; }
  else if (i < 24576) { W = Wk; WT = WkT; NN = 128; rem = i - 16384; }
  else if (i < 32768) { W = Wv; WT = WvT; NN = 128; rem = i - 24576; }
  else { W = Wo; WT = WoT; NN = 256; rem = i - 32768; }
  const int n = rem % NN, kp = rem / NN;   // kp = k-pair index
  const float v0 = W[(size_t)(2 * kp) * NN + n];
  const float v1 = W[(size_t)(2 * kp + 1) * NN + n];
  const int kdim = (WT == WqT) ? 256 : 128;
  *(unsigned*)&WT[(size_t)n * kdim + 2 * kp] = bpack2(v0, v1);
}

// ---- QKV projection: one wave per 32x32 tile, 4-deep load pipeline --------
// X side: 8 dword fp32 loads/step (strided along k, coalesced along col);
// W side: single 16B bf16 frag load (L2). No LDS, no barriers.
template <int NK, bool WisA>
__device__ inline f32x16 gemm_tile(const float* __restrict__ xb, int xcol,
                                   const short* __restrict__ wt, int wcol,
                                   int lh) {
  float xr[4][8];
  short8 wr[4];
  const short* wrow = &wt[(size_t)wcol * (NK * 16) + lh * 8];
  auto issue = [&](int s) {
    const int slot = s & 3;
    const float* p = xb + (size_t)(s * 16 + lh * 8) * NTOK + xcol;
#pragma unroll
    for (int e = 0; e < 8; ++e) xr[slot][e] = p[(size_t)e * NTOK];
    wr[slot] = *(const short8*)(wrow + s * 16);
  };
  issue(0); issue(1); issue(2);
  f32x16 acc = zero16();
#pragma unroll
  for (int ks = 0; ks < NK; ++ks) {
    if (ks + 3 < NK) issue(ks + 3);
    const int slot = ks & 3;
    short8 xa = packfrag(xr[slot]);
    if (WisA)
      acc = __builtin_amdgcn_mfma_f32_32x32x16_bf16(wr[slot], xa, acc, 0, 0, 0);
    else
      acc = __builtin_amdgcn_mfma_f32_32x32x16_bf16(xa, wr[slot], acc, 0, 0, 0);
  }
  return acc;
}

__global__ __launch_bounds__(256, 5) void proj_direct(
    const float* __restrict__ query, const float* __restrict__ key,
    const float* __restrict__ value, const short* __restrict__ WqT,
    const short* __restrict__ WkT, const short* __restrict__ WvT,
    short* __restrict__ Qbf, short* __restrict__ Kbf,
    short* __restrict__ Vbf) {
  const int wave = threadIdx.x >> 6, lane = threadIdx.x & 63;
  const int lh = lane >> 5, q32 = lane & 31;
  const int wg = blockIdx.x * 4 + wave;
  const int which = wg / 1600;
  int rem = wg - which * 1600;
  const int bt = rem / 200;
  const int t8 = rem - bt * 200;
  const int ot = t8 / 50;            // out-tile (0..3)
  const int tt = t8 - ot * 50;       // tok-tile (0..49)

  f32x16 acc;
  if (which == 0) {
    acc = gemm_tile<16, false>(query + (size_t)bt * QDIM * NTOK, tt * 32 + q32,
                               WqT, ot * 32 + q32, lh);
  } else if (which == 1) {
    acc = gemm_tile<8, false>(key + (size_t)bt * INNER * NTOK, tt * 32 + q32,
                              WkT, ot * 32 + q32, lh);
  } else {
    acc = gemm_tile<8, true>(value + (size_t)bt * INNER * NTOK, tt * 32 + q32,
                             WvT, ot * 32 + q32, lh);
  }

  if (which != 2) {
    // token-major: m = tok (rows), n = outd (cols, one head = 32)
    short* Yb = ((which == 0) ? Qbf : Kbf) +
                ((size_t)(bt * NH + ot) * NTOK) * HD;
    const float scl = (which == 0) ? 0.17677669529663687f : 1.0f;
    const int tokbase = tt * 32;
#pragma unroll
    for (int r = 0; r < 16; ++r) {
      int row = (r & 3) + 8 * (r >> 2) + 4 * lh;
      Yb[(size_t)(tokbase + row) * HD + q32] = f2b(acc[r] * scl);
    }
  } else {
    // d-major: m = i (rows), n = tok (cols)
#pragma unroll
    for (int r = 0; r < 16; ++r) {
      int irow = ot * 32 + (r & 3) + 8 * (r >> 2) + 4 * lh;
      Vbf[((size_t)bt * INNER + irow) * NTOK + tt * 32 + q32] = f2b(acc[r]);
    }
  }
}

// ---- MFMA attention (unchanged from R7) -----------------------------------
__global__ __launch_bounds__(256, 5) void attn_mfma(
    const short* __restrict__ Qb, const short* __restrict__ Kb,
    const short* __restrict__ Vb, short* __restrict__ Obf) {
  const int id = blockIdx.x;
  const int qt = id >> 5;
  const int pair = id & 31;
  const int bt = pair >> 2, h = pair & 3;
  const int wave = threadIdx.x >> 6, lane = threadIdx.x & 63;
  const int lh = lane >> 5, q32 = lane & 31;
  const int q0 = qt * 32;
  const size_t btok = ((size_t)bt * NH + h) * NTOK;
  const size_t bd = ((size_t)bt * NH + h) * HD;
  const bool hi = (lane >= 32);

  __shared__ float Cb[2][17][64];  // 8.5 KB combine buffers

  const short* Qp = &Qb[(btok + q0 + q32) * HD + lh * 8];
  const short8 bq0 = *(const short8*)(Qp);
  const short8 bq1 = *(const short8*)(Qp + 16);

  const int kstart = wave * 416 - (wave == 3 ? 32 : 0);
  const int nch = 13 - (wave >> 1);
  const short* Kp = &Kb[(btok + kstart + q32) * HD + lh * 8];
  const short* Vp = &Vb[(bd + q32) * NTOK + kstart + lh * 8];

  f32x16 o = zero16();
  float lsum = 0.f;

  short8 ak0 = *(const short8*)(Kp);
  short8 ak1 = *(const short8*)(Kp + 16);

  for (int i = 0; i < nch; ++i) {
    const int kc = i * 32;
    const int kn = (i + 1 < nch) ? kc + 32 : 0;
    short8 nk0 = *(const short8*)(Kp + (size_t)kn * HD);
    short8 nk1 = *(const short8*)(Kp + (size_t)kn * HD + 16);
    short8 av0 = *(const short8*)(Vp + kc);
    short8 av1 = *(const short8*)(Vp + kc + 16);

    f32x16 s = __builtin_amdgcn_mfma_f32_32x32x16_bf16(ak0, bq0, zero16(),
                                                       0, 0, 0);
    s = __builtin_amdgcn_mfma_f32_32x32x16_bf16(ak1, bq1, s, 0, 0, 0);

    unsigned Pd[8];
#pragma unroll
    for (int g = 0; g < 4; ++g) {
      float e0 = __expf(s[4 * g + 0]);
      float e1 = __expf(s[4 * g + 1]);
      float e2 = __expf(s[4 * g + 2]);
      float e3 = __expf(s[4 * g + 3]);
      lsum += (e0 + e1) + (e2 + e3);
      Pd[2 * g + 0] = bpack2(e0, e1);
      Pd[2 * g + 1] = bpack2(e2, e3);
    }
    unsigned Xd[8];
#pragma unroll
    for (int j = 0; j < 8; ++j)
      Xd[j] = (unsigned)__shfl_xor((int)Pd[j], 32);
    short8 pb0 = mk8(hi ? Xd[2] : Pd[0], hi ? Xd[3] : Pd[1],
                     hi ? Pd[2] : Xd[0], hi ? Pd[3] : Xd[1]);
    short8 pb1 = mk8(hi ? Xd[6] : Pd[4], hi ? Xd[7] : Pd[5],
                     hi ? Pd[6] : Xd[4], hi ? Pd[7] : Xd[5]);

    o = __builtin_amdgcn_mfma_f32_32x32x16_bf16(av0, pb0, o, 0, 0, 0);
    o = __builtin_amdgcn_mfma_f32_32x32x16_bf16(av1, pb1, o, 0, 0, 0);
    ak0 = nk0; ak1 = nk1;
  }

  lsum += __shfl_xor(lsum, 32);

  auto dump = [&](int sidx) {
#pragma unroll
    for (int r = 0; r < 16; ++r) Cb[sidx][r][lane] = o[r];
    Cb[sidx][16][lane] = lsum;
  };
  auto accum = [&](int sidx) {
#pragma unroll
    for (int r = 0; r < 16; ++r) o[r] += Cb[sidx][r][lane];
    lsum += Cb[sidx][16][lane];
  };
  if (wave == 1) dump(0);
  if (wave == 3) dump(1);
  __syncthreads();
  if (wave == 0) accum(0);
  if (wave == 2) accum(1);
  __syncthreads();
  if (wave == 2) dump(0);
  __syncthreads();
  if (wave == 0) {
    accum(0);
    const float inv = 1.f / lsum;
    short* Op = &Obf[((size_t)bt * NTOK + q0 + q32) * INNER + h * HD + lh * 4];
#pragma unroll
    for (int g = 0; g < 4; ++g) {
      unsigned d0 = bpack2(o[4 * g + 0] * inv, o[4 * g + 1] * inv);
      unsigned d1 = bpack2(o[4 * g + 2] * inv, o[4 * g + 3] * inv);
      *(uint2*)&Op[8 * g] = make_uint2(d0, d1);
    }
  }
}

// ---- output projection: both operands single-load bf16, 3-deep pipeline ---
// grid 800 x 256: wg in [0,3200): bt = wg/400; dt = out-tile; tt = tok-tile.
// A[m=dout][k=i] = WoT[dout][i]; B[n=tok][k=i] = O[tok][i] (both 16B loads).
__global__ __launch_bounds__(256, 5) void oproj_direct(
    const short* __restrict__ Obf, const short* __restrict__ WoT,
    const float* __restrict__ bo, float* __restrict__ out) {
  const int wave = threadIdx.x >> 6, lane = threadIdx.x & 63;
  const int lh = lane >> 5, q32 = lane & 31;
  const int wg = blockIdx.x * 4 + wave;
  const int bt = wg / 400;
  int rem = wg - bt * 400;
  const int dt = rem / 50;
  const int tt = rem - dt * 50;
  const int d0 = dt * 32;
  const int tok = tt * 32 + q32;

  const short* arow = &WoT[(size_t)(d0 + q32) * INNER + lh * 8];
  const short* brow = &Obf[((size_t)bt * NTOK + tok) * INNER + lh * 8];

  short8 ar[3], br[3];
  auto issue = [&](int s) {
    const int slot = s % 3;
    ar[slot] = *(const short8*)(arow + s * 16);
    br[slot] = *(const short8*)(brow + s * 16);
  };
  issue(0); issue(1);
  f32x16 acc = zero16();
#pragma unroll
  for (int ks = 0; ks < 8; ++ks) {
    if (ks + 2 < 8) issue(ks + 2);
    const int slot = ks % 3;
    acc = __builtin_amdgcn_mfma_f32_32x32x16_bf16(ar[slot], br[slot], acc,
                                                  0, 0, 0);
  }
#pragma unroll
  for (int r = 0; r < 16; ++r) {
    int row = d0 + (r & 3) + 8 * (r >> 2) + 4 * lh;
    out[((size_t)bt * QDIM + row) * NTOK + tok] = acc[r] + bo[row];
  }
}

extern "C" void kernel_launch(void* const* d_in, const int* in_sizes, int n_in,
                              void* d_out, int out_size, void* d_ws,
                              size_t ws_size, hipStream_t stream) {
  const float* query = (const float*)d_in[0];
  const float* key = (const float*)d_in[1];
  const float* value = (const float*)d_in[2];
  const float* Wq = (const float*)d_in[3];
  const float* Wk = (const float*)d_in[4];
  const float* Wv = (const float*)d_in[5];
  const float* Wo = (const float*)d_in[6];
  const float* bo = (const float*)d_in[7];
  float* out = (float*)d_out;

  const size_t arr = (size_t)BT_TOTAL * INNER * NTOK;
  short* Qbf = (short*)d_ws;
  short* Kbf = Qbf + arr;
  short* Vbf = Kbf + arr;
  short* Obf = Vbf + arr;
  short* WqT = Obf + arr;            // 128*256
  short* WkT = WqT + 128 * 256;      // 128*128
  short* WvT = WkT + 128 * 128;      // 128*128
  short* WoT = WvT + 128 * 128;      // 256*128

  wconv<<<dim3(192), 256, 0, stream>>>(Wq, Wk, Wv, Wo, WqT, WkT, WvT, WoT);
  proj_direct<<<dim3(1200), 256, 0, stream>>>(query, key, value, WqT, WkT,
                                              WvT, Qbf, Kbf, Vbf);
  attn_mfma<<<dim3(1600), 256, 0, stream>>>(Qbf, Kbf, Vbf, Obf);
  oproj_direct<<<dim3(800), 256, 0, stream>>>(Obf, WoT, bo, out);
}